// Round 1
// baseline (711.425 us; speedup 1.0000x reference)
//
#include <hip/hip_runtime.h>
#include <hip/hip_cooperative_groups.h>
#include <math.h>

namespace cg = cooperative_groups;

#define Bsz  64
#define Cch  2048
#define Kdim 768
#define Ssp  361
#define CPB  16                      // channels per staged slice
#define REGF (CPB * Ssp)             // 5776 floats = 23104 B per slice
#define NFULL 22                     // 22 full 1KB DMA issues ...
#define NTAIL 36                     // ... + 1 tail issue with 36 active lanes
#define NCG   (Cch / CPB)            // 128 channel groups
#define NSLICE (Bsz * NCG)           // 8192 slices

// ---------------------------------------------------------------------------
// Async global->LDS DMA, 16 B per lane per issue (no VGPR round-trip; the
// compiler cannot serialize it down to ~2 loads in flight like plain loads).
// LDS dest semantics: wave-uniform base + lane*16 (m104/m108).
// ---------------------------------------------------------------------------
__device__ __forceinline__ void dma16(const float* g, float* l) {
    __builtin_amdgcn_global_load_lds(
        (const __attribute__((address_space(1))) void*)(g),
        (__attribute__((address_space(3))) void*)(l),
        16, 0, 0);
}

// Stage one 23104 B slice (16 ch x 361 floats) into LDS; NW waves split the
// 23 issues; each wave drains its own vmcnt.
template <int NW>
__device__ __forceinline__ void stage_slice(const float* region, float* lds,
                                            int wv, int lane) {
    for (int i = wv; i < NFULL + 1; i += NW) {
        if (i < NFULL || lane < NTAIL)
            dma16(region + i * 256 + lane * 4, lds + i * 256);
    }
    asm volatile("s_waitcnt vmcnt(0)" ::: "memory");
}

// ===========================================================================
// FUSED cooperative kernel: qgemm -> sims -> softmax -> pool, one dispatch,
// 3 grid-wide syncs. 256 threads (4 waves), 25.6 KB LDS -> 4 blocks/CU.
// Grid is sized at launch from the occupancy query (multiple of 64 so each
// block keeps a fixed batch b = bid&63 in phases 1/3).
// ===========================================================================
__global__ __launch_bounds__(256, 4) void k_fused(
    const float* __restrict__ text, const float* __restrict__ img,
    const float* __restrict__ W,    const float* __restrict__ bias,
    float* __restrict__ qT, float* __restrict__ sims_part,
    float* __restrict__ wts, float* __restrict__ out)
{
    const int tid  = threadIdx.x;
    const int lane = tid & 63;
    const int wv   = tid >> 6;
    const int bid  = blockIdx.x;
    const int nblk = gridDim.x;

    __shared__ __align__(16) float lds[REGF];  // staged img slice
    __shared__ float aux[Ssp];                 // qL (16) / wL (361)
    __shared__ float partial[256];             // pool reduce / softmax red

    cg::grid_group grid = cg::this_grid();

    // ------------------- phase 0: qT[c][b] = text.W^T + bias ---------------
    // 8192 wave-tasks: (c-pair, b-octet). Wave-private, no block sync needed.
    for (int t = bid * 4 + wv; t < 8192; t += nblk * 4) {
        const int c0 = (t & 1023) * 2;
        const int b0 = (t >> 10) * 8;
        const float4* wA = (const float4*)(W + (size_t)c0 * Kdim);
        const float4* wB = (const float4*)(W + (size_t)(c0 + 1) * Kdim);
        const float4 a0 = wA[lane*3+0], a1 = wA[lane*3+1], a2 = wA[lane*3+2];
        const float4 g0 = wB[lane*3+0], g1 = wB[lane*3+1], g2 = wB[lane*3+2];
        const float biasA = bias[c0], biasB = bias[c0 + 1];

        for (int b = b0; b < b0 + 8; b += 2) {
            const float4* tp = (const float4*)(text + (size_t)b * Kdim);
            const float4* up = (const float4*)(text + (size_t)(b + 1) * Kdim);
            const float4 t0 = tp[lane*3+0], t1 = tp[lane*3+1], t2 = tp[lane*3+2];
            const float4 u0 = up[lane*3+0], u1 = up[lane*3+1], u2 = up[lane*3+2];

            float r00 = a0.x*t0.x + a0.y*t0.y + a0.z*t0.z + a0.w*t0.w
                      + a1.x*t1.x + a1.y*t1.y + a1.z*t1.z + a1.w*t1.w
                      + a2.x*t2.x + a2.y*t2.y + a2.z*t2.z + a2.w*t2.w;
            float r10 = g0.x*t0.x + g0.y*t0.y + g0.z*t0.z + g0.w*t0.w
                      + g1.x*t1.x + g1.y*t1.y + g1.z*t1.z + g1.w*t1.w
                      + g2.x*t2.x + g2.y*t2.y + g2.z*t2.z + g2.w*t2.w;
            float r01 = a0.x*u0.x + a0.y*u0.y + a0.z*u0.z + a0.w*u0.w
                      + a1.x*u1.x + a1.y*u1.y + a1.z*u1.z + a1.w*u1.w
                      + a2.x*u2.x + a2.y*u2.y + a2.z*u2.z + a2.w*u2.w;
            float r11 = g0.x*u0.x + g0.y*u0.y + g0.z*u0.z + g0.w*u0.w
                      + g1.x*u1.x + g1.y*u1.y + g1.z*u1.z + g1.w*u1.w
                      + g2.x*u2.x + g2.y*u2.y + g2.z*u2.z + g2.w*u2.w;
            #pragma unroll
            for (int off = 32; off; off >>= 1) {
                r00 += __shfl_xor(r00, off);
                r10 += __shfl_xor(r10, off);
                r01 += __shfl_xor(r01, off);
                r11 += __shfl_xor(r11, off);
            }
            if (lane == 0) {
                qT[(size_t)c0 * Bsz + b]           = r00 + biasA;
                qT[(size_t)(c0 + 1) * Bsz + b]     = r10 + biasB;
                qT[(size_t)c0 * Bsz + b + 1]       = r01 + biasA;
                qT[(size_t)(c0 + 1) * Bsz + b + 1] = r11 + biasB;
            }
        }
    }

    __threadfence();
    grid.sync();
    __threadfence();

    // ------------------- phase 1: partial sims (HBM pass, 189 MB) ----------
    // slice sl -> (b = sl&63, cg = sl>>6); nblk % 64 == 0 keeps b fixed/block.
    for (int sl = bid; sl < NSLICE; sl += nblk) {
        const int b   = sl & (Bsz - 1);
        const int cgi = sl >> 6;
        if (tid < CPB)
            aux[tid] = qT[(size_t)(cgi * CPB + tid) * Bsz + b];
        const float* region = img + ((size_t)b * Cch + (size_t)cgi * CPB) * Ssp;
        stage_slice<4>(region, lds, wv, lane);
        __syncthreads();
        for (int s = tid; s < Ssp; s += 256) {
            float acc = 0.f;
            #pragma unroll
            for (int c = 0; c < CPB; c++)
                acc += aux[c] * lds[c * Ssp + s];   // stride-1 across lanes
            sims_part[((size_t)b * NCG + cgi) * Ssp + s] = acc;
        }
        __syncthreads();   // protect lds/aux before next stage
    }

    __threadfence();
    grid.sync();
    __threadfence();

    // ------------------- phase 2: reduce 128 partials + softmax ------------
    if (bid < Bsz) {
        const int b = bid;
        const float* sp = sims_part + (size_t)b * NCG * Ssp;
        float sa, sb = -1e30f;
        {
            float a = 0.f;
            for (int g0 = 0; g0 < NCG; g0 += 16) {
                float v[16];
                #pragma unroll
                for (int j = 0; j < 16; j++) v[j] = sp[(size_t)(g0 + j) * Ssp + tid];
                #pragma unroll
                for (int j = 0; j < 16; j++) a += v[j];
            }
            sa = a;
        }
        if (tid < Ssp - 256) {   // second s per thread (105 active)
            float a = 0.f;
            for (int g0 = 0; g0 < NCG; g0 += 16) {
                float v[16];
                #pragma unroll
                for (int j = 0; j < 16; j++) v[j] = sp[(size_t)(g0 + j) * Ssp + tid + 256];
                #pragma unroll
                for (int j = 0; j < 16; j++) a += v[j];
            }
            sb = a;
        }
        float m = fmaxf(sa, sb);
        #pragma unroll
        for (int off = 32; off; off >>= 1) m = fmaxf(m, __shfl_xor(m, off));
        if (lane == 0) partial[wv] = m;
        __syncthreads();
        m = fmaxf(fmaxf(partial[0], partial[1]), fmaxf(partial[2], partial[3]));
        __syncthreads();
        const float ea = __expf(sa - m);
        const float eb = (tid < Ssp - 256) ? __expf(sb - m) : 0.f;
        float l = ea + eb;
        #pragma unroll
        for (int off = 32; off; off >>= 1) l += __shfl_xor(l, off);
        if (lane == 0) partial[wv] = l;
        __syncthreads();
        l = partial[0] + partial[1] + partial[2] + partial[3];
        wts[(size_t)b * Ssp + tid] = ea / l;
        if (tid < Ssp - 256) wts[(size_t)b * Ssp + tid + 256] = eb / l;
    }

    __threadfence();
    grid.sync();
    __threadfence();

    // ------------------- phase 3: weighted pool (img pass 2, ~L3-hot) ------
    {
        const int b = bid & (Bsz - 1);      // fixed per block since nblk%64==0
        for (int s = tid; s < Ssp; s += 256)
            aux[s] = wts[(size_t)b * Ssp + s];
    }
    __syncthreads();
    for (int sl = bid; sl < NSLICE; sl += nblk) {
        const int b   = sl & (Bsz - 1);
        const int cgi = sl >> 6;
        const float* region = img + ((size_t)b * Cch + (size_t)cgi * CPB) * Ssp;
        stage_slice<4>(region, lds, wv, lane);
        __syncthreads();
        // thread -> (c = tid&15, s-phase g = tid>>4); lds addr = 9c+s mod 32
        // across a wave -> <=2-way bank aliasing (free, m136)
        const int c = tid & 15;
        const int g = tid >> 4;
        float p = 0.f;
        for (int s = g; s < Ssp; s += 16)
            p += lds[c * Ssp + s] * aux[s];
        partial[tid] = p;
        __syncthreads();
        if (tid < CPB) {
            float r = 0.f;
            #pragma unroll
            for (int gg = 0; gg < 16; gg++) r += partial[gg * 16 + tid];
            out[(size_t)b * Cch + (size_t)cgi * CPB + tid] = r;
        }
        __syncthreads();
    }
}

// ===========================================================================
// Fallback path: the proven 4-kernel pipeline (unchanged), used only if
// cooperative launch is rejected (e.g. under graph capture).
// ===========================================================================
__global__ __launch_bounds__(256) void k_qgemm(
    const float* __restrict__ text, const float* __restrict__ W,
    const float* __restrict__ bias, float* __restrict__ qT)
{
    const int lane = threadIdx.x & 63;
    const int wv   = threadIdx.x >> 6;
    const int c0   = blockIdx.x * 8 + wv * 2;
    const int b0   = blockIdx.y * 8;

    const float4* wA = (const float4*)(W + (size_t)c0 * Kdim);
    const float4* wB = (const float4*)(W + (size_t)(c0 + 1) * Kdim);
    const float4 a0 = wA[lane*3+0], a1 = wA[lane*3+1], a2 = wA[lane*3+2];
    const float4 g0 = wB[lane*3+0], g1 = wB[lane*3+1], g2 = wB[lane*3+2];
    const float biasA = bias[c0], biasB = bias[c0 + 1];

    for (int b = b0; b < b0 + 8; b += 2) {
        const float4* tp = (const float4*)(text + (size_t)b * Kdim);
        const float4* up = (const float4*)(text + (size_t)(b + 1) * Kdim);
        const float4 t0 = tp[lane*3+0], t1 = tp[lane*3+1], t2 = tp[lane*3+2];
        const float4 u0 = up[lane*3+0], u1 = up[lane*3+1], u2 = up[lane*3+2];

        float r00 = a0.x*t0.x + a0.y*t0.y + a0.z*t0.z + a0.w*t0.w
                  + a1.x*t1.x + a1.y*t1.y + a1.z*t1.z + a1.w*t1.w
                  + a2.x*t2.x + a2.y*t2.y + a2.z*t2.z + a2.w*t2.w;
        float r10 = g0.x*t0.x + g0.y*t0.y + g0.z*t0.z + g0.w*t0.w
                  + g1.x*t1.x + g1.y*t1.y + g1.z*t1.z + g1.w*t1.w
                  + g2.x*t2.x + g2.y*t2.y + g2.z*t2.z + g2.w*t2.w;
        float r01 = a0.x*u0.x + a0.y*u0.y + a0.z*u0.z + a0.w*u0.w
                  + a1.x*u1.x + a1.y*u1.y + a1.z*u1.z + a1.w*u1.w
                  + a2.x*u2.x + a2.y*u2.y + a2.z*u2.z + a2.w*u2.w;
        float r11 = g0.x*u0.x + g0.y*u0.y + g0.z*u0.z + g0.w*u0.w
                  + g1.x*u1.x + g1.y*u1.y + g1.z*u1.z + g1.w*u1.w
                  + g2.x*u2.x + g2.y*u2.y + g2.z*u2.z + g2.w*u2.w;
        #pragma unroll
        for (int off = 32; off; off >>= 1) {
            r00 += __shfl_xor(r00, off);
            r10 += __shfl_xor(r10, off);
            r01 += __shfl_xor(r01, off);
            r11 += __shfl_xor(r11, off);
        }
        if (lane == 0) {
            qT[(size_t)c0 * Bsz + b]           = r00 + biasA;
            qT[(size_t)(c0 + 1) * Bsz + b]     = r10 + biasB;
            qT[(size_t)c0 * Bsz + b + 1]       = r01 + biasA;
            qT[(size_t)(c0 + 1) * Bsz + b + 1] = r11 + biasB;
        }
    }
}

__global__ __launch_bounds__(384) void k_sims(
    const float* __restrict__ img, const float* __restrict__ qT,
    float* __restrict__ sims_part)
{
    const int b  = blockIdx.x;
    const int cgi = blockIdx.y;
    const int tid = threadIdx.x;
    const int lane = tid & 63;
    const int wv   = tid >> 6;

    __shared__ float lds[REGF];
    __shared__ float qL[CPB];

    if (tid < CPB) qL[tid] = qT[(size_t)(cgi * CPB + tid) * Bsz + b];

    const float* region = img + ((size_t)b * Cch + (size_t)cgi * CPB) * Ssp;
    stage_slice<6>(region, lds, wv, lane);
    __syncthreads();

    if (tid < Ssp) {
        float acc = 0.f;
        #pragma unroll
        for (int c = 0; c < CPB; c++)
            acc += qL[c] * lds[c * Ssp + tid];
        sims_part[((size_t)b * NCG + cgi) * Ssp + tid] = acc;
    }
}

__global__ __launch_bounds__(384) void k_wts(
    const float* __restrict__ sims_part, float* __restrict__ wts)
{
    const int b   = blockIdx.x;
    const int tid = threadIdx.x;
    const int lane = tid & 63;
    const int wv   = tid >> 6;

    __shared__ float red[6];

    float s0 = -1e30f;
    if (tid < Ssp) {
        const float* sp = sims_part + (size_t)b * NCG * Ssp + tid;
        float a = 0.f;
        for (int g0 = 0; g0 < NCG; g0 += 16) {
            float v[16];
            #pragma unroll
            for (int j = 0; j < 16; j++) v[j] = sp[(size_t)(g0 + j) * Ssp];
            #pragma unroll
            for (int j = 0; j < 16; j++) a += v[j];
        }
        s0 = a;
    }

    float m = s0;
    #pragma unroll
    for (int off = 32; off; off >>= 1) m = fmaxf(m, __shfl_xor(m, off));
    if (lane == 0) red[wv] = m;
    __syncthreads();
    m = red[0];
    #pragma unroll
    for (int w = 1; w < 6; w++) m = fmaxf(m, red[w]);
    __syncthreads();

    const float e0 = (tid < Ssp) ? __expf(s0 - m) : 0.f;
    float l = e0;
    #pragma unroll
    for (int off = 32; off; off >>= 1) l += __shfl_xor(l, off);
    if (lane == 0) red[wv] = l;
    __syncthreads();
    l = red[0] + red[1] + red[2] + red[3] + red[4] + red[5];

    if (tid < Ssp)
        wts[(size_t)b * Ssp + tid] = e0 / l;
}

__global__ __launch_bounds__(384) void k_pool(
    const float* __restrict__ img, const float* __restrict__ wts,
    float* __restrict__ out)
{
    const int b   = blockIdx.x;
    const int cgi = blockIdx.y;
    const int tid = threadIdx.x;
    const int lane = tid & 63;
    const int wv   = tid >> 6;

    __shared__ float lds[REGF];
    __shared__ float wL[Ssp];
    __shared__ float partial[6 * CPB];

    if (tid < Ssp) wL[tid] = wts[(size_t)b * Ssp + tid];

    const float* region = img + ((size_t)b * Cch + (size_t)cgi * CPB) * Ssp;
    stage_slice<6>(region, lds, wv, lane);
    __syncthreads();

    const int c    = lane & 15;
    const int sl   = lane >> 4;
    const int s_lo = sl * 90 + (sl > 0 ? 1 : 0);
    const int s_hi = s_lo + (sl > 0 ? 90 : 91);

    float p = 0.f;
    for (int s = s_lo + wv; s < s_hi; s += 6)
        p += lds[c * Ssp + s] * wL[s];

    p += __shfl_xor(p, 16);
    p += __shfl_xor(p, 32);
    if (lane < CPB) partial[wv * CPB + lane] = p;
    __syncthreads();

    if (tid < CPB) {
        float r = partial[tid];
        #pragma unroll
        for (int w = 1; w < 6; w++) r += partial[w * CPB + tid];
        out[(size_t)b * Cch + (size_t)cgi * CPB + tid] = r;
    }
}

// ---------------------------------------------------------------------------
extern "C" void kernel_launch(void* const* d_in, const int* in_sizes, int n_in,
                              void* d_out, int out_size, void* d_ws, size_t ws_size,
                              hipStream_t stream) {
    const float* text = (const float*)d_in[0];   // [64, 768]
    const float* img  = (const float*)d_in[1];   // [64, 2048, 19, 19]
    const float* W    = (const float*)d_in[2];   // [2048, 768]
    const float* bias = (const float*)d_in[3];   // [2048]
    float* out = (float*)d_out;                  // [64, 2048]

    // ws: qT (512 KB) + sims_part (11.8 MB) + wts (90 KB)
    float* qT        = (float*)d_ws;
    float* sims_part = qT + (size_t)Cch * Bsz;
    float* wts       = sims_part + (size_t)Bsz * NCG * Ssp;

    // One-time grid sizing for the cooperative launch (host-side queries only;
    // graph-capture safe). Grid must be co-resident and a multiple of 64.
    static int mode = 0;            // 0 = uninit, 1 = cooperative, 2 = fallback
    static int nblk = 1024;
    if (mode == 0) {
        int bpc = 0;
        if (hipOccupancyMaxActiveBlocksPerMultiprocessor(
                &bpc, reinterpret_cast<const void*>(&k_fused), 256, 0) != hipSuccess
            || bpc < 1)
            bpc = 2;
        int cus = 256;
        hipDeviceProp_t prop;
        int dev = 0;
        if (hipGetDevice(&dev) == hipSuccess &&
            hipGetDeviceProperties(&prop, dev) == hipSuccess &&
            prop.multiProcessorCount > 0)
            cus = prop.multiProcessorCount;
        long long nb = (long long)bpc * cus;
        if (nb > 2048) nb = 2048;
        nb -= nb % 64;
        if (nb < 64) nb = 64;
        nblk = (int)nb;
        mode = 1;
    }

    bool done = false;
    if (mode != 2) {
        void* args[8] = {(void*)&text, (void*)&img, (void*)&W, (void*)&bias,
                         (void*)&qT, (void*)&sims_part, (void*)&wts, (void*)&out};
        hipError_t e = hipLaunchCooperativeKernel(
            reinterpret_cast<const void*>(&k_fused),
            dim3(nblk), dim3(256), args, 0, stream);
        if (e == hipSuccess) {
            done = true;
        } else {
            mode = 2;
            (void)hipGetLastError();   // clear sticky error before fallback
        }
    }
    if (!done) {
        k_qgemm<<<dim3(256, 8),   256, 0, stream>>>(text, W, bias, qT);
        k_sims <<<dim3(Bsz, NCG), 384, 0, stream>>>(img, qT, sims_part);
        k_wts  <<<dim3(Bsz),      384, 0, stream>>>(sims_part, wts);
        k_pool <<<dim3(Bsz, NCG), 384, 0, stream>>>(img, wts, out);
    }
}

// Round 3
// 319.045 us; speedup vs baseline: 2.2299x; 2.2299x over previous
//
#include <hip/hip_runtime.h>
#include <math.h>

#define Bsz  64
#define Cch  2048
#define Kdim 768
#define Ssp  361
#define CPB  16                      // channels per block (sims staging)
#define REGF (CPB * Ssp)             // 5776 floats = 23104 B per block slice
#define NFULL 22                     // 22 full 1KB DMA issues ...
#define NTAIL 36                     // ... + 1 tail issue with 36 active lanes
#define NCG   (Cch / CPB)            // 128 channel groups

// ---------------------------------------------------------------------------
// Async global->LDS DMA, 16 B per lane per issue. DMA consumes no VGPRs, so
// the compiler cannot sink/serialize it (rounds 3-5 showed VGPR-minimizing
// scheduling keeps only ~2 plain loads in flight -> 2 TB/s latency wall).
// LDS dest semantics: wave-uniform base + lane*16 (m104/m108).
// ---------------------------------------------------------------------------
__device__ __forceinline__ void dma16(const float* g, float* l) {
    __builtin_amdgcn_global_load_lds(
        (const __attribute__((address_space(1))) void*)(g),
        (__attribute__((address_space(3))) void*)(l),
        16, 0, 0);
}

// Stage one 23104 B slice (16 channels x 361 floats, 16 B-aligned) into LDS.
// 6 waves split 23 issues; each wave then drains its own vmcnt.
__device__ __forceinline__ void stage_slice(const float* region, float* lds,
                                            int wv, int lane) {
    for (int i = wv; i < NFULL + 1; i += 6) {
        if (i < NFULL || lane < NTAIL)
            dma16(region + i * 256 + lane * 4, lds + i * 256);
    }
    asm volatile("s_waitcnt vmcnt(0)" ::: "memory");
}

// ---------------------------------------------------------------------------
// K1: qT[c][b] = dot(text[b,:], W[c,:]) + bias[c]
// grid = (256, 8) x 256; wave owns 2 channels, 8 batches in pairs. ~8 us.
// ---------------------------------------------------------------------------
__global__ __launch_bounds__(256) void k_qgemm(
    const float* __restrict__ text, const float* __restrict__ W,
    const float* __restrict__ bias, float* __restrict__ qT)
{
    const int lane = threadIdx.x & 63;
    const int wv   = threadIdx.x >> 6;
    const int c0   = blockIdx.x * 8 + wv * 2;
    const int b0   = blockIdx.y * 8;

    const float4* wA = (const float4*)(W + (size_t)c0 * Kdim);
    const float4* wB = (const float4*)(W + (size_t)(c0 + 1) * Kdim);
    const float4 a0 = wA[lane*3+0], a1 = wA[lane*3+1], a2 = wA[lane*3+2];
    const float4 g0 = wB[lane*3+0], g1 = wB[lane*3+1], g2 = wB[lane*3+2];
    const float biasA = bias[c0], biasB = bias[c0 + 1];

    for (int b = b0; b < b0 + 8; b += 2) {
        const float4* tp = (const float4*)(text + (size_t)b * Kdim);
        const float4* up = (const float4*)(text + (size_t)(b + 1) * Kdim);
        const float4 t0 = tp[lane*3+0], t1 = tp[lane*3+1], t2 = tp[lane*3+2];
        const float4 u0 = up[lane*3+0], u1 = up[lane*3+1], u2 = up[lane*3+2];

        float r00 = a0.x*t0.x + a0.y*t0.y + a0.z*t0.z + a0.w*t0.w
                  + a1.x*t1.x + a1.y*t1.y + a1.z*t1.z + a1.w*t1.w
                  + a2.x*t2.x + a2.y*t2.y + a2.z*t2.z + a2.w*t2.w;
        float r10 = g0.x*t0.x + g0.y*t0.y + g0.z*t0.z + g0.w*t0.w
                  + g1.x*t1.x + g1.y*t1.y + g1.z*t1.z + g1.w*t1.w
                  + g2.x*t2.x + g2.y*t2.y + g2.z*t2.z + g2.w*t2.w;
        float r01 = a0.x*u0.x + a0.y*u0.y + a0.z*u0.z + a0.w*u0.w
                  + a1.x*u1.x + a1.y*u1.y + a1.z*u1.z + a1.w*u1.w
                  + a2.x*u2.x + a2.y*u2.y + a2.z*u2.z + a2.w*u2.w;
        float r11 = g0.x*u0.x + g0.y*u0.y + g0.z*u0.z + g0.w*u0.w
                  + g1.x*u1.x + g1.y*u1.y + g1.z*u1.z + g1.w*u1.w
                  + g2.x*u2.x + g2.y*u2.y + g2.z*u2.z + g2.w*u2.w;
        #pragma unroll
        for (int off = 32; off; off >>= 1) {
            r00 += __shfl_xor(r00, off);
            r10 += __shfl_xor(r10, off);
            r01 += __shfl_xor(r01, off);
            r11 += __shfl_xor(r11, off);
        }
        if (lane == 0) {
            qT[(size_t)c0 * Bsz + b]           = r00 + biasA;
            qT[(size_t)(c0 + 1) * Bsz + b]     = r10 + biasB;
            qT[(size_t)c0 * Bsz + b + 1]       = r01 + biasA;
            qT[(size_t)(c0 + 1) * Bsz + b + 1] = r11 + biasB;
        }
    }
}

// ---------------------------------------------------------------------------
// K2: partial sims via DMA-staged LDS. grid (b=64, cg=128) x 384.
// Stage 16-channel slice (23 KB) with global_load_lds, then thread s<361
// does 16 conflict-free LDS reads + FMAs. This is the HBM pass (189 MB).
// 8192 independent blocks give the CU scheduler free stage/compute overlap.
// ---------------------------------------------------------------------------
__global__ __launch_bounds__(384) void k_sims(
    const float* __restrict__ img, const float* __restrict__ qT,
    float* __restrict__ sims_part)
{
    const int b  = blockIdx.x;
    const int cg = blockIdx.y;
    const int tid = threadIdx.x;
    const int lane = tid & 63;
    const int wv   = tid >> 6;

    __shared__ float lds[REGF];
    __shared__ float qL[CPB];

    if (tid < CPB) qL[tid] = qT[(size_t)(cg * CPB + tid) * Bsz + b];

    const float* region = img + ((size_t)b * Cch + (size_t)cg * CPB) * Ssp;
    stage_slice(region, lds, wv, lane);
    __syncthreads();

    if (tid < Ssp) {
        float acc = 0.f;
        #pragma unroll
        for (int c = 0; c < CPB; c++)
            acc += qL[c] * lds[c * Ssp + tid];
        sims_part[((size_t)b * NCG + cg) * Ssp + tid] = acc;
    }
}

// ---------------------------------------------------------------------------
// K3: weights. grid = 64 x 384; sums the 128 partials (L2-hot), block
// softmax, writes PRE-NORMALIZED weights.
// ---------------------------------------------------------------------------
__global__ __launch_bounds__(384) void k_wts(
    const float* __restrict__ sims_part, float* __restrict__ wts)
{
    const int b   = blockIdx.x;
    const int tid = threadIdx.x;
    const int lane = tid & 63;
    const int wv   = tid >> 6;

    __shared__ float red[6];

    float s0 = -1e30f;
    if (tid < Ssp) {
        const float* sp = sims_part + (size_t)b * NCG * Ssp + tid;
        float a = 0.f;
        for (int g0 = 0; g0 < 128; g0 += 16) {
            float v[16];
            #pragma unroll
            for (int j = 0; j < 16; j++) v[j] = sp[(size_t)(g0 + j) * Ssp];
            #pragma unroll
            for (int j = 0; j < 16; j++) a += v[j];
        }
        s0 = a;
    }

    float m = s0;
    #pragma unroll
    for (int off = 32; off; off >>= 1) m = fmaxf(m, __shfl_xor(m, off));
    if (lane == 0) red[wv] = m;
    __syncthreads();
    m = red[0];
    #pragma unroll
    for (int w = 1; w < 6; w++) m = fmaxf(m, red[w]);
    __syncthreads();

    const float e0 = (tid < Ssp) ? __expf(s0 - m) : 0.f;
    float l = e0;
    #pragma unroll
    for (int off = 32; off; off >>= 1) l += __shfl_xor(l, off);
    if (lane == 0) red[wv] = l;
    __syncthreads();
    l = red[0] + red[1] + red[2] + red[3] + red[4] + red[5];

    if (tid < Ssp)
        wts[(size_t)b * Ssp + tid] = e0 / l;
}

// ---------------------------------------------------------------------------
// K4: weighted pooling, DIRECT reads (no LDS staging). Round-1 counters
// proved this pass is ~L3-resident (FETCH ~200 MB for 378 MB logical), so
// staging was pure overhead (common-mistake #7): 23 KB DMA + vmcnt(0) drain
// + 2 barriers + idle tail lanes, for data used exactly once.
// New shape: grid (b=64, cg=16) x 256. Wave owns channel rows; lane = s
// (coalesced 256 B per instr); weights broadcast from 1.4 KB LDS copy.
// 4 rows in flight per wave -> 24 independent loads covering L3 latency.
// ---------------------------------------------------------------------------
__global__ __launch_bounds__(256) void k_pool(
    const float* __restrict__ img, const float* __restrict__ wts,
    float* __restrict__ out)
{
    const int b    = blockIdx.x;
    const int cg   = blockIdx.y;          // 16 groups x 128 channels
    const int tid  = threadIdx.x;
    const int lane = tid & 63;
    const int wv   = tid >> 6;

    __shared__ float wL[Ssp];
    for (int s = tid; s < Ssp; s += 256)
        wL[s] = wts[(size_t)b * Ssp + s];
    __syncthreads();

    // preload this lane's 6 weights once (s = lane + 64k), reused for all rows
    float wreg[6];
    #pragma unroll
    for (int k = 0; k < 6; k++) {
        const int s = lane + 64 * k;
        wreg[k] = (s < Ssp) ? wL[s] : 0.f;   // stride-1 lanes: conflict-free
    }

    const float* base = img + ((size_t)b * Cch + (size_t)cg * 128) * Ssp;
    const int c0 = wv * 32;                  // wave's 32 channels

    for (int i = 0; i < 32; i += 4) {
        const float* r0 = base + (size_t)(c0 + i + 0) * Ssp;
        const float* r1 = base + (size_t)(c0 + i + 1) * Ssp;
        const float* r2 = base + (size_t)(c0 + i + 2) * Ssp;
        const float* r3 = base + (size_t)(c0 + i + 3) * Ssp;

        float a0 = 0.f, a1 = 0.f, a2 = 0.f, a3 = 0.f;
        #pragma unroll
        for (int k = 0; k < 6; k++) {
            const int s = lane + 64 * k;
            const bool ok = (s < Ssp);
            const float v0 = ok ? r0[s] : 0.f;
            const float v1 = ok ? r1[s] : 0.f;
            const float v2 = ok ? r2[s] : 0.f;
            const float v3 = ok ? r3[s] : 0.f;
            a0 += v0 * wreg[k];
            a1 += v1 * wreg[k];
            a2 += v2 * wreg[k];
            a3 += v3 * wreg[k];
        }
        #pragma unroll
        for (int off = 32; off; off >>= 1) {
            a0 += __shfl_xor(a0, off);
            a1 += __shfl_xor(a1, off);
            a2 += __shfl_xor(a2, off);
            a3 += __shfl_xor(a3, off);
        }
        if (lane == 0) {
            float* o = out + (size_t)b * Cch + (size_t)cg * 128 + c0 + i;
            o[0] = a0; o[1] = a1; o[2] = a2; o[3] = a3;
        }
    }
}

// ---------------------------------------------------------------------------
extern "C" void kernel_launch(void* const* d_in, const int* in_sizes, int n_in,
                              void* d_out, int out_size, void* d_ws, size_t ws_size,
                              hipStream_t stream) {
    const float* text = (const float*)d_in[0];   // [64, 768]
    const float* img  = (const float*)d_in[1];   // [64, 2048, 19, 19]
    const float* W    = (const float*)d_in[2];   // [2048, 768]
    const float* bias = (const float*)d_in[3];   // [2048]
    float* out = (float*)d_out;                  // [64, 2048]

    // ws: qT (512 KB) + sims_part (11.8 MB) + wts (90 KB)
    float* qT        = (float*)d_ws;
    float* sims_part = qT + (size_t)Cch * Bsz;
    float* wts       = sims_part + (size_t)Bsz * NCG * Ssp;

    k_qgemm<<<dim3(256, 8),   256, 0, stream>>>(text, W, bias, qT);
    k_sims <<<dim3(Bsz, NCG), 384, 0, stream>>>(img, qT, sims_part);
    k_wts  <<<dim3(Bsz),      384, 0, stream>>>(sims_part, wts);
    k_pool <<<dim3(Bsz, 16),  256, 0, stream>>>(img, wts, out);
}